// Round 14
// baseline (70.684 us; speedup 1.0000x reference)
//
#include <hip/hip_runtime.h>

// FutureEncoder as banded flash-attention on MFMA (bf16 split-precision).
// Round 14 = DIAGNOSTIC on the R13 structure (current best, 25.4us).
// REPS=4 identical passes (idempotent; output bit-identical) so the dispatch
// reaches ~100us and surfaces in the top-5 profile rows with its counters.
// Opaque per-rep register dependency defeats cross-rep CSE. Extra
// __syncthreads per rep prevents WAR on the reduce buffer across reps.
// Cold/warm split: rep1 pays compulsory HBM reads; reps 2-4 are cache-warm.

typedef float f32x4 __attribute__((ext_vector_type(4)));
typedef unsigned int u32;
typedef u32 u32x4 __attribute__((ext_vector_type(4)));
typedef short bf16x8 __attribute__((ext_vector_type(8)));

namespace {
constexpr int kB = 2, kS = 4096, kH = 1024;
constexpr int kWaves = 8;                    // 512 threads
constexpr int kTilesT = 16;                  // t's per block
constexpr int kBlocks = kB * kS / kTilesT;   // 512 -> 2 blocks/CU
constexpr int kXCD = 8;
constexpr int kHW = kH / kWaves;             // 128 h-cols per wave
constexpr int kREPS = 4;
}

__device__ __forceinline__ u32 f32u(float x){ return __builtin_bit_cast(u32, x); }
__device__ __forceinline__ float uf32(u32 x){ return __builtin_bit_cast(float, x); }
__device__ __forceinline__ u32 pkbf(float a, float b){ return (f32u(b)&0xFFFF0000u)|(f32u(a)>>16); }

struct Frag2 { bf16x8 hi, lo; };
__device__ __forceinline__ Frag2 split2(float4 u, float4 v) {
  float fu[8] = {u.x,u.y,u.z,u.w,v.x,v.y,v.z,v.w};
  u32 hw[4], lw[4];
#pragma unroll
  for (int i = 0; i < 4; ++i) {
    float a = fu[2*i], b = fu[2*i+1];
    u32 ua = f32u(a), ub = f32u(b);
    hw[i] = (ub & 0xFFFF0000u) | (ua >> 16);
    float la = a - uf32(ua & 0xFFFF0000u);
    float lb = b - uf32(ub & 0xFFFF0000u);
    lw[i] = (f32u(lb) & 0xFFFF0000u) | (f32u(la) >> 16);
  }
  Frag2 r;
  u32x4 h = {hw[0],hw[1],hw[2],hw[3]}, l = {lw[0],lw[1],lw[2],lw[3]};
  r.hi = __builtin_bit_cast(bf16x8, h);
  r.lo = __builtin_bit_cast(bf16x8, l);
  return r;
}

#define MFMA(A,B,C) __builtin_amdgcn_mfma_f32_16x16x32_bf16((A),(B),(C),0,0,0)

template <int REPS>
__global__ __launch_bounds__(512, 4)
void fenc_mfma(const float* __restrict__ x, float* __restrict__ out) {
  __shared__ float red[kWaves][2][4][64];   // 16 KB: per-wave S^T partials
  const int lane = (int)(threadIdx.x & 63), wid = (int)(threadIdx.x >> 6);
  const int g = lane >> 4, c = lane & 15;

  // XCD strip swizzle (512 % 8 == 0 -> bijective)
  const int vb  = (int)(blockIdx.x % kXCD)*(kBlocks/kXCD) + (int)(blockIdx.x / kXCD);
  const int t0g = vb * kTilesT;
  const int b   = t0g / kS, t0 = t0g % kS;
  const float* __restrict__ xb0 = x + (size_t)b*kS*kH;
  float* __restrict__ ob0 = out + (size_t)b*kS*kH;
  const int hw0 = kHW * wid;

  int opaque = 0;   // always 0; opaque to the compiler after the asm below

  for (int rep = 0; rep < REPS; ++rep) {
    asm volatile("" : "+v"(opaque));        // defeat cross-rep CSE/hoisting
    const float* __restrict__ xb = xb0 + opaque;
    float* __restrict__ ob = ob0 + opaque;

    // ---- QK^T (swapped: A = K windows, B = Q), k-split over H ----
    const int ra = (t0 + 1 + c  < kS) ? (t0 + 1 + c)  : (kS - 1);
    const int rb = (t0 + 17 + c < kS) ? (t0 + 17 + c) : (kS - 1);
    const float* qp  = xb + (size_t)(t0 + c)*kH + hw0;
    const float* kpa = xb + (size_t)ra*kH + hw0;
    const float* kpb = xb + (size_t)rb*kH + hw0;

    // 6 independent accumulation chains (depth 4 each)
    f32x4 aHH = {0.f,0.f,0.f,0.f}, aHL = aHH, aLH = aHH;
    f32x4 bHH = aHH, bHL = aHH, bLH = aHH;
    __builtin_amdgcn_s_setprio(1);
#pragma unroll
    for (int ks = 0; ks < 4; ++ks) {
      const int off = ks*32 + g*8;
      float4 q0 = *(const float4*)(qp  + off), q1 = *(const float4*)(qp  + off + 4);
      float4 a0 = *(const float4*)(kpa + off), a1 = *(const float4*)(kpa + off + 4);
      float4 b0 = *(const float4*)(kpb + off), b1 = *(const float4*)(kpb + off + 4);
      Frag2 fq = split2(q0, q1), fa = split2(a0, a1), fb = split2(b0, b1);
      aHH = MFMA(fa.hi, fq.hi, aHH);
      aHL = MFMA(fa.hi, fq.lo, aHL);
      aLH = MFMA(fa.lo, fq.hi, aLH);
      bHH = MFMA(fb.hi, fq.hi, bHH);
      bHL = MFMA(fb.hi, fq.lo, bHL);
      bLH = MFMA(fb.lo, fq.hi, bLH);
    }
    __builtin_amdgcn_s_setprio(0);
    f32x4 accA = (aHH + aHL) + aLH;
    f32x4 accB = (bHH + bHL) + bLH;

    // ---- V-gather prefetch (depends only on x; hides under reduce) ----
    const float* vrow[8];
#pragma unroll
    for (int i = 0; i < 8; ++i) {
      const int rv = t0 + 1 + 8*g + i;
      vrow[i] = xb + (size_t)((rv < kS) ? rv : (kS - 1))*kH + hw0 + c;
    }
    float vf[8][8];
#pragma unroll
    for (int nt = 0; nt < 8; ++nt)
#pragma unroll
      for (int i = 0; i < 8; ++i) vf[nt][i] = vrow[i][16*nt];

    // ---- cross-wave reduce of S^T partials ----
#pragma unroll
    for (int r = 0; r < 4; ++r) {
      red[wid][0][r][lane] = accA[r];
      red[wid][1][r][lane] = accB[r];
    }
    __syncthreads();
#pragma unroll
    for (int w = 0; w < kWaves; ++w) {
      if (w != wid) {
#pragma unroll
        for (int r = 0; r < 4; ++r) {
          accA[r] += red[w][0][r][lane];
          accB[r] += red[w][1][r][lane];
        }
      }
    }
    __syncthreads();   // WAR guard: next rep rewrites `red`

    // ---- softmax (all 32 windows of t = t0+c live in this lane) ----
    float p[2][4];
    float vmax = -1e30f;
#pragma unroll
    for (int T = 0; T < 2; ++T)
#pragma unroll
      for (int r = 0; r < 4; ++r) {
        const int w = 16*T + 4*g + r;
        const bool val = (w >= c) && (w < c + 16) && (t0 + 1 + w < kS);
        const float sv = val ? (T ? accB[r] : accA[r]) : -1e30f;
        p[T][r] = sv;
        vmax = fmaxf(vmax, sv);
      }
    vmax = fmaxf(vmax, __shfl_xor(vmax, 16, 64));
    vmax = fmaxf(vmax, __shfl_xor(vmax, 32, 64));
    float psum = 0.f;
#pragma unroll
    for (int T = 0; T < 2; ++T)
#pragma unroll
      for (int r = 0; r < 4; ++r) {
        const int w = 16*T + 4*g + r;
        const bool val = (w >= c) && (w < c + 16) && (t0 + 1 + w < kS);
        const float e = val ? __expf(p[T][r] - vmax) : 0.f;
        p[T][r] = e;
        psum += e;
      }
    psum += __shfl_xor(psum, 16, 64);
    psum += __shfl_xor(psum, 32, 64);
    const float inv = (psum > 0.f) ? (1.f / psum) : 0.f;
#pragma unroll
    for (int T = 0; T < 2; ++T)
#pragma unroll
      for (int r = 0; r < 4; ++r) p[T][r] *= inv;

    // ---- build P^T A-frag ----
    const int se = (g & 1)*32 + c, so = se + 16;
    float slot[8];
#pragma unroll
    for (int r = 0; r < 4; ++r) {
      const float e0 = __shfl(p[0][r], se, 64), e1 = __shfl(p[1][r], se, 64);
      const float o0 = __shfl(p[0][r], so, 64), o1 = __shfl(p[1][r], so, 64);
      slot[r]     = (g >> 1) ? e1 : e0;
      slot[4 + r] = (g >> 1) ? o1 : o0;
    }
    u32x4 pw = { pkbf(slot[0],slot[1]), pkbf(slot[2],slot[3]),
                 pkbf(slot[4],slot[5]), pkbf(slot[6],slot[7]) };
    const bf16x8 pa = __builtin_bit_cast(bf16x8, pw);

    // ---- PV (V already in registers) ----
    f32x4 o[8];
    __builtin_amdgcn_s_setprio(1);
#pragma unroll
    for (int nt = 0; nt < 8; ++nt) {
      u32x4 vw = { pkbf(vf[nt][0],vf[nt][1]), pkbf(vf[nt][2],vf[nt][3]),
                   pkbf(vf[nt][4],vf[nt][5]), pkbf(vf[nt][6],vf[nt][7]) };
      const bf16x8 vfrag = __builtin_bit_cast(bf16x8, vw);
      f32x4 z = {0.f,0.f,0.f,0.f};
      o[nt] = MFMA(pa, vfrag, z);
    }
    __builtin_amdgcn_s_setprio(0);

    // ---- store ----
    float* orow[4];
#pragma unroll
    for (int r = 0; r < 4; ++r)
      orow[r] = ob + (size_t)(t0 + 4*g + r)*kH + hw0 + c;
#pragma unroll
    for (int nt = 0; nt < 8; ++nt)
#pragma unroll
      for (int r = 0; r < 4; ++r)
        orow[r][16*nt] = o[nt][r];
  }
}

extern "C" void kernel_launch(void* const* d_in, const int* in_sizes, int n_in,
                              void* d_out, int out_size, void* d_ws, size_t ws_size,
                              hipStream_t stream) {
  const float* x = (const float*)d_in[0];
  float* out = (float*)d_out;
  hipLaunchKernelGGL(fenc_mfma<kREPS>, dim3(kBlocks), dim3(512), 0, stream, x, out);
}

// Round 15
// 48.814 us; speedup vs baseline: 1.4481x; 1.4481x over previous
//
#include <hip/hip_runtime.h>

// FutureEncoder as banded flash-attention on MFMA (bf16 split-precision).
// out[b,t,:] = softmax_j(x[t]·x[t+1+j]) · x[t+1+j], j in [0,16), fp32 I/O.
//
// Round 15: occupancy doubling. R14 diagnostic: warm-structure cost 15us,
// MfmaUtil 4.4%, VALUBusy 24.5%, occupancy 38.8% (grid-capped at 4 waves/SIMD),
// VGPR=64 (compiler sank the V-prefetch to keep 64). Fix: split each tile's
// PV output across 2 blocks (h-halves), DUPLICATING the cheap QK+softmax
// (compute is 4-25% busy; latency hiding is the scarce resource).
// Grid 512->1024 blocks, 8192 waves = 32/CU. Per-wave PV state halves so
// launch_bounds(512,8) can hold VGPR<=64 for 8 waves/SIMD. Also: b128 LDS
// reduce (2 writes + 14 reads instead of 8 + 56 b32).

typedef float f32x4 __attribute__((ext_vector_type(4)));
typedef unsigned int u32;
typedef u32 u32x4 __attribute__((ext_vector_type(4)));
typedef short bf16x8 __attribute__((ext_vector_type(8)));

namespace {
constexpr int kB = 2, kS = 4096, kH = 1024;
constexpr int kWaves = 8;                    // 512 threads
constexpr int kTilesT = 16;                  // t's per tile
constexpr int kHSplit = 2;                   // PV h-halves per tile
constexpr int kBlocks = kHSplit * kB * kS / kTilesT;   // 1024
constexpr int kXCD = 8;
constexpr int kHW  = kH / kWaves;            // 128 QK h-cols per wave
constexpr int kHPV = kH / kHSplit / kWaves;  // 64 PV h-cols per wave
}

__device__ __forceinline__ u32 f32u(float x){ return __builtin_bit_cast(u32, x); }
__device__ __forceinline__ float uf32(u32 x){ return __builtin_bit_cast(float, x); }
__device__ __forceinline__ u32 pkbf(float a, float b){ return (f32u(b)&0xFFFF0000u)|(f32u(a)>>16); }

struct Frag2 { bf16x8 hi, lo; };
__device__ __forceinline__ Frag2 split2(float4 u, float4 v) {
  float fu[8] = {u.x,u.y,u.z,u.w,v.x,v.y,v.z,v.w};
  u32 hw[4], lw[4];
#pragma unroll
  for (int i = 0; i < 4; ++i) {
    float a = fu[2*i], b = fu[2*i+1];
    u32 ua = f32u(a), ub = f32u(b);
    hw[i] = (ub & 0xFFFF0000u) | (ua >> 16);
    float la = a - uf32(ua & 0xFFFF0000u);
    float lb = b - uf32(ub & 0xFFFF0000u);
    lw[i] = (f32u(lb) & 0xFFFF0000u) | (f32u(la) >> 16);
  }
  Frag2 r;
  u32x4 h = {hw[0],hw[1],hw[2],hw[3]}, l = {lw[0],lw[1],lw[2],lw[3]};
  r.hi = __builtin_bit_cast(bf16x8, h);
  r.lo = __builtin_bit_cast(bf16x8, l);
  return r;
}

#define MFMA(A,B,C) __builtin_amdgcn_mfma_f32_16x16x32_bf16((A),(B),(C),0,0,0)

__global__ __launch_bounds__(512, 8)
void fenc_mfma(const float* __restrict__ x, float* __restrict__ out) {
  __shared__ f32x4 red[kWaves][2][64];      // 16 KB: per-wave S^T partials (b128)
  const int lane = (int)(threadIdx.x & 63), wid = (int)(threadIdx.x >> 6);
  const int g = lane >> 4, c = lane & 15;

  // XCD strip swizzle (1024 % 8 == 0 -> bijective). Adjacent vb = the two
  // h-halves of one tile -> same rows, same XCD L2.
  const int vb  = (int)(blockIdx.x % kXCD)*(kBlocks/kXCD) + (int)(blockIdx.x / kXCD);
  const int tile = vb >> 1, q = vb & 1;     // q = which PV h-half
  const int t0g = tile * kTilesT;
  const int b   = t0g / kS, t0 = t0g % kS;
  const float* __restrict__ xb = x + (size_t)b*kS*kH;
  float* __restrict__ ob = out + (size_t)b*kS*kH;
  const int hw0  = kHW * wid;                       // QK k-slice (full H union)
  const int hpv0 = q * (kH / kHSplit) + kHPV * wid; // PV h-slice (64 cols)

  // ---- QK^T (swapped: A = K windows, B = Q), k-split over H ----
  const int ra = (t0 + 1 + c  < kS) ? (t0 + 1 + c)  : (kS - 1);
  const int rb = (t0 + 17 + c < kS) ? (t0 + 17 + c) : (kS - 1);
  const float* qp  = xb + (size_t)(t0 + c)*kH + hw0;
  const float* kpa = xb + (size_t)ra*kH + hw0;
  const float* kpb = xb + (size_t)rb*kH + hw0;

  // 6 independent accumulation chains (depth 4 each) -> MFMA pipelines.
  f32x4 aHH = {0.f,0.f,0.f,0.f}, aHL = aHH, aLH = aHH;
  f32x4 bHH = aHH, bHL = aHH, bLH = aHH;
  __builtin_amdgcn_s_setprio(1);
#pragma unroll
  for (int ks = 0; ks < 4; ++ks) {
    const int off = ks*32 + g*8;
    float4 q0 = *(const float4*)(qp  + off), q1 = *(const float4*)(qp  + off + 4);
    float4 a0 = *(const float4*)(kpa + off), a1 = *(const float4*)(kpa + off + 4);
    float4 b0 = *(const float4*)(kpb + off), b1 = *(const float4*)(kpb + off + 4);
    Frag2 fq = split2(q0, q1), fa = split2(a0, a1), fb = split2(b0, b1);
    aHH = MFMA(fa.hi, fq.hi, aHH);
    aHL = MFMA(fa.hi, fq.lo, aHL);
    aLH = MFMA(fa.lo, fq.hi, aLH);
    bHH = MFMA(fb.hi, fq.hi, bHH);
    bHL = MFMA(fb.hi, fq.lo, bHL);
    bLH = MFMA(fb.lo, fq.hi, bLH);
  }
  __builtin_amdgcn_s_setprio(0);
  f32x4 accA = (aHH + aHL) + aLH;
  f32x4 accB = (bHH + bHL) + bLH;

  // ---- V row pointers for this block's h-half ----
  const float* vrow[8];
#pragma unroll
  for (int i = 0; i < 8; ++i) {
    const int rv = t0 + 1 + 8*g + i;
    vrow[i] = xb + (size_t)((rv < kS) ? rv : (kS - 1))*kH + hpv0 + c;
  }

  // ---- cross-wave reduce of S^T partials (b128, lane-linear) ----
  red[wid][0][lane] = accA;
  red[wid][1][lane] = accB;
  __syncthreads();
#pragma unroll
  for (int w = 0; w < kWaves; ++w) {
    if (w != wid) {
      const f32x4 pa4 = red[w][0][lane];
      const f32x4 pb4 = red[w][1][lane];
      accA += pa4;
      accB += pb4;
    }
  }

  // ---- softmax (per lane: all 32 windows of t = t0+c) ----
  float p[2][4];
  float vmax = -1e30f;
#pragma unroll
  for (int T = 0; T < 2; ++T)
#pragma unroll
    for (int r = 0; r < 4; ++r) {
      const int w = 16*T + 4*g + r;
      const bool val = (w >= c) && (w < c + 16) && (t0 + 1 + w < kS);
      const float sv = val ? (T ? accB[r] : accA[r]) : -1e30f;
      p[T][r] = sv;
      vmax = fmaxf(vmax, sv);
    }
  vmax = fmaxf(vmax, __shfl_xor(vmax, 16, 64));
  vmax = fmaxf(vmax, __shfl_xor(vmax, 32, 64));
  float psum = 0.f;
#pragma unroll
  for (int T = 0; T < 2; ++T)
#pragma unroll
    for (int r = 0; r < 4; ++r) {
      const int w = 16*T + 4*g + r;
      const bool val = (w >= c) && (w < c + 16) && (t0 + 1 + w < kS);
      const float e = val ? __expf(p[T][r] - vmax) : 0.f;
      p[T][r] = e;
      psum += e;
    }
  psum += __shfl_xor(psum, 16, 64);
  psum += __shfl_xor(psum, 32, 64);
  const float inv = (psum > 0.f) ? (1.f / psum) : 0.f;
#pragma unroll
  for (int T = 0; T < 2; ++T)
#pragma unroll
    for (int r = 0; r < 4; ++r) p[T][r] *= inv;

  // ---- build P^T A-frag: lane needs P[t=c][w = 8g+i], i=0..7 ----
  const int se = (g & 1)*32 + c, so = se + 16;
  float slot[8];
#pragma unroll
  for (int r = 0; r < 4; ++r) {
    const float e0 = __shfl(p[0][r], se, 64), e1 = __shfl(p[1][r], se, 64);
    const float o0 = __shfl(p[0][r], so, 64), o1 = __shfl(p[1][r], so, 64);
    slot[r]     = (g >> 1) ? e1 : e0;
    slot[4 + r] = (g >> 1) ? o1 : o0;
  }
  u32x4 pw = { pkbf(slot[0],slot[1]), pkbf(slot[2],slot[3]),
               pkbf(slot[4],slot[5]), pkbf(slot[6],slot[7]) };
  const bf16x8 pa = __builtin_bit_cast(bf16x8, pw);

  // ---- PV: O[t][h] over this block's 64 h-cols per wave ----
  f32x4 o[4];
  __builtin_amdgcn_s_setprio(1);
#pragma unroll
  for (int nt = 0; nt < 4; ++nt) {
    float vf[8];
#pragma unroll
    for (int i = 0; i < 8; ++i) vf[i] = vrow[i][16*nt];
    u32x4 vw = { pkbf(vf[0],vf[1]), pkbf(vf[2],vf[3]),
                 pkbf(vf[4],vf[5]), pkbf(vf[6],vf[7]) };
    const bf16x8 vfrag = __builtin_bit_cast(bf16x8, vw);
    f32x4 z = {0.f,0.f,0.f,0.f};
    o[nt] = MFMA(pa, vfrag, z);
  }
  __builtin_amdgcn_s_setprio(0);

  // ---- store: O[t = t0+4g+r][h = hpv0 + 16nt + c] ----
  float* orow[4];
#pragma unroll
  for (int r = 0; r < 4; ++r)
    orow[r] = ob + (size_t)(t0 + 4*g + r)*kH + hpv0 + c;
#pragma unroll
  for (int nt = 0; nt < 4; ++nt)
#pragma unroll
    for (int r = 0; r < 4; ++r)
      orow[r][16*nt] = o[nt][r];
}

extern "C" void kernel_launch(void* const* d_in, const int* in_sizes, int n_in,
                              void* d_out, int out_size, void* d_ws, size_t ws_size,
                              hipStream_t stream) {
  const float* x = (const float*)d_in[0];
  float* out = (float*)d_out;
  hipLaunchKernelGGL(fenc_mfma, dim3(kBlocks), dim3(512), 0, stream, x, out);
}

// Round 16
// 34.680 us; speedup vs baseline: 2.0382x; 1.4075x over previous
//
#include <hip/hip_runtime.h>

// FutureEncoder as banded flash-attention on MFMA (bf16 split-precision).
// out[b,t,:] = softmax_j(x[t]·x[t+1+j]) · x[t+1+j], j in [0,16), fp32 I/O.
//
// Round 16: R15's h-split geometry (1024 blocks -> 4 blocks/CU possible) but
// with __launch_bounds__(512,4). R15's (512,8) forced VGPR=32 + ~70MB of
// scratch spills (WRITE 104MB) -> 48us. Bound 4 lets the compiler pick its
// natural allocation; R13's full-PV kernel chose 64 under the same bound and
// this kernel has half the PV state, so <=64 (the 8-waves/SIMD threshold,
// m69) is expected WITHOUT forcing. Residency = min(grid 4/CU, LDS 16KB,
// VGPR) -> 32 waves/CU if <=64. Spills gone either way.

typedef float f32x4 __attribute__((ext_vector_type(4)));
typedef unsigned int u32;
typedef u32 u32x4 __attribute__((ext_vector_type(4)));
typedef short bf16x8 __attribute__((ext_vector_type(8)));

namespace {
constexpr int kB = 2, kS = 4096, kH = 1024;
constexpr int kWaves = 8;                    // 512 threads
constexpr int kTilesT = 16;                  // t's per tile
constexpr int kHSplit = 2;                   // PV h-halves per tile
constexpr int kBlocks = kHSplit * kB * kS / kTilesT;   // 1024
constexpr int kXCD = 8;
constexpr int kHW  = kH / kWaves;            // 128 QK h-cols per wave
constexpr int kHPV = kH / kHSplit / kWaves;  // 64 PV h-cols per wave
}

__device__ __forceinline__ u32 f32u(float x){ return __builtin_bit_cast(u32, x); }
__device__ __forceinline__ float uf32(u32 x){ return __builtin_bit_cast(float, x); }
__device__ __forceinline__ u32 pkbf(float a, float b){ return (f32u(b)&0xFFFF0000u)|(f32u(a)>>16); }

struct Frag2 { bf16x8 hi, lo; };
__device__ __forceinline__ Frag2 split2(float4 u, float4 v) {
  float fu[8] = {u.x,u.y,u.z,u.w,v.x,v.y,v.z,v.w};
  u32 hw[4], lw[4];
#pragma unroll
  for (int i = 0; i < 4; ++i) {
    float a = fu[2*i], b = fu[2*i+1];
    u32 ua = f32u(a), ub = f32u(b);
    hw[i] = (ub & 0xFFFF0000u) | (ua >> 16);
    float la = a - uf32(ua & 0xFFFF0000u);
    float lb = b - uf32(ub & 0xFFFF0000u);
    lw[i] = (f32u(lb) & 0xFFFF0000u) | (f32u(la) >> 16);
  }
  Frag2 r;
  u32x4 h = {hw[0],hw[1],hw[2],hw[3]}, l = {lw[0],lw[1],lw[2],lw[3]};
  r.hi = __builtin_bit_cast(bf16x8, h);
  r.lo = __builtin_bit_cast(bf16x8, l);
  return r;
}

#define MFMA(A,B,C) __builtin_amdgcn_mfma_f32_16x16x32_bf16((A),(B),(C),0,0,0)

__global__ __launch_bounds__(512, 4)
void fenc_mfma(const float* __restrict__ x, float* __restrict__ out) {
  __shared__ f32x4 red[kWaves][2][64];      // 16 KB: per-wave S^T partials (b128)
  const int lane = (int)(threadIdx.x & 63), wid = (int)(threadIdx.x >> 6);
  const int g = lane >> 4, c = lane & 15;

  // XCD strip swizzle (1024 % 8 == 0 -> bijective). Adjacent vb = the two
  // h-halves of one tile -> same rows, same XCD L2.
  const int vb  = (int)(blockIdx.x % kXCD)*(kBlocks/kXCD) + (int)(blockIdx.x / kXCD);
  const int tile = vb >> 1, q = vb & 1;     // q = which PV h-half
  const int t0g = tile * kTilesT;
  const int b   = t0g / kS, t0 = t0g % kS;
  const float* __restrict__ xb = x + (size_t)b*kS*kH;
  float* __restrict__ ob = out + (size_t)b*kS*kH;
  const int hw0  = kHW * wid;                       // QK k-slice (full H union)
  const int hpv0 = q * (kH / kHSplit) + kHPV * wid; // PV h-slice (64 cols)

  // ---- QK^T (swapped: A = K windows, B = Q), k-split over H ----
  const int ra = (t0 + 1 + c  < kS) ? (t0 + 1 + c)  : (kS - 1);
  const int rb = (t0 + 17 + c < kS) ? (t0 + 17 + c) : (kS - 1);
  const float* qp  = xb + (size_t)(t0 + c)*kH + hw0;
  const float* kpa = xb + (size_t)ra*kH + hw0;
  const float* kpb = xb + (size_t)rb*kH + hw0;

  // 6 independent accumulation chains (depth 4 each) -> MFMA pipelines.
  f32x4 aHH = {0.f,0.f,0.f,0.f}, aHL = aHH, aLH = aHH;
  f32x4 bHH = aHH, bHL = aHH, bLH = aHH;
  __builtin_amdgcn_s_setprio(1);
#pragma unroll
  for (int ks = 0; ks < 4; ++ks) {
    const int off = ks*32 + g*8;
    float4 q0 = *(const float4*)(qp  + off), q1 = *(const float4*)(qp  + off + 4);
    float4 a0 = *(const float4*)(kpa + off), a1 = *(const float4*)(kpa + off + 4);
    float4 b0 = *(const float4*)(kpb + off), b1 = *(const float4*)(kpb + off + 4);
    Frag2 fq = split2(q0, q1), fa = split2(a0, a1), fb = split2(b0, b1);
    aHH = MFMA(fa.hi, fq.hi, aHH);
    aHL = MFMA(fa.hi, fq.lo, aHL);
    aLH = MFMA(fa.lo, fq.hi, aLH);
    bHH = MFMA(fb.hi, fq.hi, bHH);
    bHL = MFMA(fb.hi, fq.lo, bHL);
    bLH = MFMA(fb.lo, fq.hi, bLH);
  }
  __builtin_amdgcn_s_setprio(0);
  f32x4 accA = (aHH + aHL) + aLH;
  f32x4 accB = (bHH + bHL) + bLH;

  // ---- V row pointers for this block's h-half ----
  const float* vrow[8];
#pragma unroll
  for (int i = 0; i < 8; ++i) {
    const int rv = t0 + 1 + 8*g + i;
    vrow[i] = xb + (size_t)((rv < kS) ? rv : (kS - 1))*kH + hpv0 + c;
  }

  // ---- cross-wave reduce of S^T partials (b128, lane-linear) ----
  red[wid][0][lane] = accA;
  red[wid][1][lane] = accB;
  __syncthreads();
#pragma unroll
  for (int w = 0; w < kWaves; ++w) {
    if (w != wid) {
      accA += red[w][0][lane];
      accB += red[w][1][lane];
    }
  }

  // ---- softmax (per lane: all 32 windows of t = t0+c) ----
  float p[2][4];
  float vmax = -1e30f;
#pragma unroll
  for (int T = 0; T < 2; ++T)
#pragma unroll
    for (int r = 0; r < 4; ++r) {
      const int w = 16*T + 4*g + r;
      const bool val = (w >= c) && (w < c + 16) && (t0 + 1 + w < kS);
      const float sv = val ? (T ? accB[r] : accA[r]) : -1e30f;
      p[T][r] = sv;
      vmax = fmaxf(vmax, sv);
    }
  vmax = fmaxf(vmax, __shfl_xor(vmax, 16, 64));
  vmax = fmaxf(vmax, __shfl_xor(vmax, 32, 64));
  float psum = 0.f;
#pragma unroll
  for (int T = 0; T < 2; ++T)
#pragma unroll
    for (int r = 0; r < 4; ++r) {
      const int w = 16*T + 4*g + r;
      const bool val = (w >= c) && (w < c + 16) && (t0 + 1 + w < kS);
      const float e = val ? __expf(p[T][r] - vmax) : 0.f;
      p[T][r] = e;
      psum += e;
    }
  psum += __shfl_xor(psum, 16, 64);
  psum += __shfl_xor(psum, 32, 64);
  const float inv = (psum > 0.f) ? (1.f / psum) : 0.f;
#pragma unroll
  for (int T = 0; T < 2; ++T)
#pragma unroll
    for (int r = 0; r < 4; ++r) p[T][r] *= inv;

  // ---- build P^T A-frag: lane needs P[t=c][w = 8g+i], i=0..7 ----
  const int se = (g & 1)*32 + c, so = se + 16;
  float slot[8];
#pragma unroll
  for (int r = 0; r < 4; ++r) {
    const float e0 = __shfl(p[0][r], se, 64), e1 = __shfl(p[1][r], se, 64);
    const float o0 = __shfl(p[0][r], so, 64), o1 = __shfl(p[1][r], so, 64);
    slot[r]     = (g >> 1) ? e1 : e0;
    slot[4 + r] = (g >> 1) ? o1 : o0;
  }
  u32x4 pw = { pkbf(slot[0],slot[1]), pkbf(slot[2],slot[3]),
               pkbf(slot[4],slot[5]), pkbf(slot[6],slot[7]) };
  const bf16x8 pa = __builtin_bit_cast(bf16x8, pw);

  // ---- PV: O[t][h] over this block's 64 h-cols per wave ----
  f32x4 o[4];
  __builtin_amdgcn_s_setprio(1);
#pragma unroll
  for (int nt = 0; nt < 4; ++nt) {
    float vf[8];
#pragma unroll
    for (int i = 0; i < 8; ++i) vf[i] = vrow[i][16*nt];
    u32x4 vw = { pkbf(vf[0],vf[1]), pkbf(vf[2],vf[3]),
                 pkbf(vf[4],vf[5]), pkbf(vf[6],vf[7]) };
    const bf16x8 vfrag = __builtin_bit_cast(bf16x8, vw);
    f32x4 z = {0.f,0.f,0.f,0.f};
    o[nt] = MFMA(pa, vfrag, z);
  }
  __builtin_amdgcn_s_setprio(0);

  // ---- store: O[t = t0+4g+r][h = hpv0 + 16nt + c] ----
  float* orow[4];
#pragma unroll
  for (int r = 0; r < 4; ++r)
    orow[r] = ob + (size_t)(t0 + 4*g + r)*kH + hpv0 + c;
#pragma unroll
  for (int nt = 0; nt < 4; ++nt)
#pragma unroll
    for (int r = 0; r < 4; ++r)
      orow[r][16*nt] = o[nt][r];
}

extern "C" void kernel_launch(void* const* d_in, const int* in_sizes, int n_in,
                              void* d_out, int out_size, void* d_ws, size_t ws_size,
                              hipStream_t stream) {
  const float* x = (const float*)d_in[0];
  float* out = (float*)d_out;
  hipLaunchKernelGGL(fenc_mfma, dim3(kBlocks), dim3(512), 0, stream, x, out);
}

// Round 17
// 29.339 us; speedup vs baseline: 2.4093x; 1.1821x over previous
//
#include <hip/hip_runtime.h>

// FutureEncoder as banded flash-attention on MFMA (bf16 split-precision).
// out[b,t,:] = softmax_j(x[t]·x[t+1+j]) · x[t+1+j], j in [0,16), fp32 I/O.
//
// Round 17: occupancy via FINER SPLIT (not duplication). 1024-thr blocks,
// 16 waves: each wave k-splits QK over 64 cols (2 k-steps, 12 MFMA) and
// PV over 64 h-cols (4 tiles). 512 blocks x 16 waves = 8192 waves; with
// VGPR<=64 (launch_bounds(1024,8)) -> 2 blocks/CU = 32 waves/CU (100%).
// R15's forced-64 spilled because it kept FULL QK state; here QK state is
// halved and PV quartered vs the 64-VGPR R13, so 64 should fit cleanly.
// Costs: 16-way LDS reduce (32KB, tree adds), 16x duplicated softmax
// (cheap), one 1024-thread barrier.

typedef float f32x4 __attribute__((ext_vector_type(4)));
typedef unsigned int u32;
typedef u32 u32x4 __attribute__((ext_vector_type(4)));
typedef short bf16x8 __attribute__((ext_vector_type(8)));

namespace {
constexpr int kB = 2, kS = 4096, kH = 1024;
constexpr int kWaves = 16;                   // 1024 threads
constexpr int kTilesT = 16;                  // t's per block
constexpr int kBlocks = kB * kS / kTilesT;   // 512 -> 2 blocks/CU
constexpr int kXCD = 8;
constexpr int kHW = kH / kWaves;             // 64 cols per wave (QK k & PV h)
}

__device__ __forceinline__ u32 f32u(float x){ return __builtin_bit_cast(u32, x); }
__device__ __forceinline__ float uf32(u32 x){ return __builtin_bit_cast(float, x); }
__device__ __forceinline__ u32 pkbf(float a, float b){ return (f32u(b)&0xFFFF0000u)|(f32u(a)>>16); }

struct Frag2 { bf16x8 hi, lo; };
__device__ __forceinline__ Frag2 split2(float4 u, float4 v) {
  float fu[8] = {u.x,u.y,u.z,u.w,v.x,v.y,v.z,v.w};
  u32 hw[4], lw[4];
#pragma unroll
  for (int i = 0; i < 4; ++i) {
    float a = fu[2*i], b = fu[2*i+1];
    u32 ua = f32u(a), ub = f32u(b);
    hw[i] = (ub & 0xFFFF0000u) | (ua >> 16);
    float la = a - uf32(ua & 0xFFFF0000u);
    float lb = b - uf32(ub & 0xFFFF0000u);
    lw[i] = (f32u(lb) & 0xFFFF0000u) | (f32u(la) >> 16);
  }
  Frag2 r;
  u32x4 h = {hw[0],hw[1],hw[2],hw[3]}, l = {lw[0],lw[1],lw[2],lw[3]};
  r.hi = __builtin_bit_cast(bf16x8, h);
  r.lo = __builtin_bit_cast(bf16x8, l);
  return r;
}

#define MFMA(A,B,C) __builtin_amdgcn_mfma_f32_16x16x32_bf16((A),(B),(C),0,0,0)

__global__ __launch_bounds__(1024, 8)
void fenc_mfma(const float* __restrict__ x, float* __restrict__ out) {
  __shared__ f32x4 red[kWaves][2][64];      // 32 KB: per-wave S^T partials
  const int lane = (int)(threadIdx.x & 63), wid = (int)(threadIdx.x >> 6);
  const int g = lane >> 4, c = lane & 15;

  // XCD strip swizzle (512 % 8 == 0 -> bijective)
  const int vb  = (int)(blockIdx.x % kXCD)*(kBlocks/kXCD) + (int)(blockIdx.x / kXCD);
  const int t0g = vb * kTilesT;
  const int b   = t0g / kS, t0 = t0g % kS;
  const float* __restrict__ xb = x + (size_t)b*kS*kH;
  float* __restrict__ ob = out + (size_t)b*kS*kH;
  const int hw0 = kHW * wid;                // this wave's 64-col slice

  // ---- QK^T (swapped: A = K windows, B = Q), 64-col k-slice, 2 k-steps ----
  const int ra = (t0 + 1 + c  < kS) ? (t0 + 1 + c)  : (kS - 1);
  const int rb = (t0 + 17 + c < kS) ? (t0 + 17 + c) : (kS - 1);
  const float* qp  = xb + (size_t)(t0 + c)*kH + hw0;
  const float* kpa = xb + (size_t)ra*kH + hw0;
  const float* kpb = xb + (size_t)rb*kH + hw0;

  // 6 independent accumulation chains (depth 2 each)
  f32x4 aHH = {0.f,0.f,0.f,0.f}, aHL = aHH, aLH = aHH;
  f32x4 bHH = aHH, bHL = aHH, bLH = aHH;
  __builtin_amdgcn_s_setprio(1);
#pragma unroll
  for (int ks = 0; ks < 2; ++ks) {
    const int off = ks*32 + g*8;
    float4 q0 = *(const float4*)(qp  + off), q1 = *(const float4*)(qp  + off + 4);
    float4 a0 = *(const float4*)(kpa + off), a1 = *(const float4*)(kpa + off + 4);
    float4 b0 = *(const float4*)(kpb + off), b1 = *(const float4*)(kpb + off + 4);
    Frag2 fq = split2(q0, q1), fa = split2(a0, a1), fb = split2(b0, b1);
    aHH = MFMA(fa.hi, fq.hi, aHH);
    aHL = MFMA(fa.hi, fq.lo, aHL);
    aLH = MFMA(fa.lo, fq.hi, aLH);
    bHH = MFMA(fb.hi, fq.hi, bHH);
    bHL = MFMA(fb.hi, fq.lo, bHL);
    bLH = MFMA(fb.lo, fq.hi, bLH);
  }
  __builtin_amdgcn_s_setprio(0);
  f32x4 pA = (aHH + aHL) + aLH;
  f32x4 pB = (bHH + bHL) + bLH;

  // ---- V row pointers for this wave's 64-col h-slice (same cols as QK
  //      k-slice -> rows are L1/L2-warm from the A-frag loads) ----
  const float* vrow[8];
#pragma unroll
  for (int i = 0; i < 8; ++i) {
    const int rv = t0 + 1 + 8*g + i;
    vrow[i] = xb + (size_t)((rv < kS) ? rv : (kS - 1))*kH + hw0 + c;
  }

  // ---- cross-wave reduce of S^T partials (16-way, pairwise tree) ----
  red[wid][0][lane] = pA;
  red[wid][1][lane] = pB;
  __syncthreads();
  f32x4 accA = {0.f,0.f,0.f,0.f}, accB = {0.f,0.f,0.f,0.f};
#pragma unroll
  for (int w = 0; w < kWaves; w += 2) {
    accA += red[w][0][lane] + red[w+1][0][lane];
    accB += red[w][1][lane] + red[w+1][1][lane];
  }

  // ---- softmax (per lane: all 32 windows of t = t0+c) ----
  float p[2][4];
  float vmax = -1e30f;
#pragma unroll
  for (int T = 0; T < 2; ++T)
#pragma unroll
    for (int r = 0; r < 4; ++r) {
      const int w = 16*T + 4*g + r;
      const bool val = (w >= c) && (w < c + 16) && (t0 + 1 + w < kS);
      const float sv = val ? (T ? accB[r] : accA[r]) : -1e30f;
      p[T][r] = sv;
      vmax = fmaxf(vmax, sv);
    }
  vmax = fmaxf(vmax, __shfl_xor(vmax, 16, 64));
  vmax = fmaxf(vmax, __shfl_xor(vmax, 32, 64));
  float psum = 0.f;
#pragma unroll
  for (int T = 0; T < 2; ++T)
#pragma unroll
    for (int r = 0; r < 4; ++r) {
      const int w = 16*T + 4*g + r;
      const bool val = (w >= c) && (w < c + 16) && (t0 + 1 + w < kS);
      const float e = val ? __expf(p[T][r] - vmax) : 0.f;
      p[T][r] = e;
      psum += e;
    }
  psum += __shfl_xor(psum, 16, 64);
  psum += __shfl_xor(psum, 32, 64);
  const float inv = (psum > 0.f) ? (1.f / psum) : 0.f;
#pragma unroll
  for (int T = 0; T < 2; ++T)
#pragma unroll
    for (int r = 0; r < 4; ++r) p[T][r] *= inv;

  // ---- build P^T A-frag: lane needs P[t=c][w = 8g+i], i=0..7 ----
  const int se = (g & 1)*32 + c, so = se + 16;
  float slot[8];
#pragma unroll
  for (int r = 0; r < 4; ++r) {
    const float e0 = __shfl(p[0][r], se, 64), e1 = __shfl(p[1][r], se, 64);
    const float o0 = __shfl(p[0][r], so, 64), o1 = __shfl(p[1][r], so, 64);
    slot[r]     = (g >> 1) ? e1 : e0;
    slot[4 + r] = (g >> 1) ? o1 : o0;
  }
  u32x4 pw = { pkbf(slot[0],slot[1]), pkbf(slot[2],slot[3]),
               pkbf(slot[4],slot[5]), pkbf(slot[6],slot[7]) };
  const bf16x8 pa = __builtin_bit_cast(bf16x8, pw);

  // ---- PV: O[t][h] over this wave's 64 h-cols (4 tiles) ----
  f32x4 o[4];
  __builtin_amdgcn_s_setprio(1);
#pragma unroll
  for (int nt = 0; nt < 4; ++nt) {
    float vf[8];
#pragma unroll
    for (int i = 0; i < 8; ++i) vf[i] = vrow[i][16*nt];
    u32x4 vw = { pkbf(vf[0],vf[1]), pkbf(vf[2],vf[3]),
                 pkbf(vf[4],vf[5]), pkbf(vf[6],vf[7]) };
    const bf16x8 vfrag = __builtin_bit_cast(bf16x8, vw);
    f32x4 z = {0.f,0.f,0.f,0.f};
    o[nt] = MFMA(pa, vfrag, z);
  }
  __builtin_amdgcn_s_setprio(0);

  // ---- store: O[t = t0+4g+r][h = hw0 + 16nt + c] ----
  float* orow[4];
#pragma unroll
  for (int r = 0; r < 4; ++r)
    orow[r] = ob + (size_t)(t0 + 4*g + r)*kH + hw0 + c;
#pragma unroll
  for (int nt = 0; nt < 4; ++nt)
#pragma unroll
    for (int r = 0; r < 4; ++r)
      orow[r][16*nt] = o[nt][r];
}

extern "C" void kernel_launch(void* const* d_in, const int* in_sizes, int n_in,
                              void* d_out, int out_size, void* d_ws, size_t ws_size,
                              hipStream_t stream) {
  const float* x = (const float*)d_in[0];
  float* out = (float*)d_out;
  hipLaunchKernelGGL(fenc_mfma, dim3(kBlocks), dim3(1024), 0, stream, x, out);
}

// Round 18
// 25.542 us; speedup vs baseline: 2.7674x; 1.1486x over previous
//
#include <hip/hip_runtime.h>

// FutureEncoder as banded flash-attention on MFMA (bf16 split-precision).
// out[b,t,:] = softmax_j(x[t]·x[t+1+j]) · x[t+1+j], j in [0,16), fp32 I/O.
//
// Round 19 = R13 (best, 25.4us) + two L2-pressure levers:
//  1) NON-TEMPORAL output stores: output (33MB) is never re-read; nt stores
//     stop it from dirtying the per-XCD 4MB L2, where the 4.2MB input strip
//     already barely fits. R14 showed 2.5x FETCH amplification = L2 thrash.
//  2) CU-pair swizzle: within an XCD, pair adjacent tiles on the same CU
//     (j -> (j%32)*2 + j/32) so the two co-resident blocks share 17/33 rows
//     through L1/L2 instead of owning disjoint row sets 512 t apart.

typedef float f32x4 __attribute__((ext_vector_type(4)));
typedef unsigned int u32;
typedef u32 u32x4 __attribute__((ext_vector_type(4)));
typedef short bf16x8 __attribute__((ext_vector_type(8)));

namespace {
constexpr int kB = 2, kS = 4096, kH = 1024;
constexpr int kWaves = 8;                    // 512 threads
constexpr int kTilesT = 16;                  // t's per block
constexpr int kBlocks = kB * kS / kTilesT;   // 512 -> 2 blocks/CU
constexpr int kXCD = 8;
constexpr int kCPX = kBlocks / kXCD;         // 64 tiles per XCD strip
constexpr int kHW = kH / kWaves;             // 128 h-cols per wave
}

__device__ __forceinline__ u32 f32u(float x){ return __builtin_bit_cast(u32, x); }
__device__ __forceinline__ float uf32(u32 x){ return __builtin_bit_cast(float, x); }
__device__ __forceinline__ u32 pkbf(float a, float b){ return (f32u(b)&0xFFFF0000u)|(f32u(a)>>16); }

struct Frag2 { bf16x8 hi, lo; };
__device__ __forceinline__ Frag2 split2(float4 u, float4 v) {
  float fu[8] = {u.x,u.y,u.z,u.w,v.x,v.y,v.z,v.w};
  u32 hw[4], lw[4];
#pragma unroll
  for (int i = 0; i < 4; ++i) {
    float a = fu[2*i], b = fu[2*i+1];
    u32 ua = f32u(a), ub = f32u(b);
    hw[i] = (ub & 0xFFFF0000u) | (ua >> 16);
    float la = a - uf32(ua & 0xFFFF0000u);
    float lb = b - uf32(ub & 0xFFFF0000u);
    lw[i] = (f32u(lb) & 0xFFFF0000u) | (f32u(la) >> 16);
  }
  Frag2 r;
  u32x4 h = {hw[0],hw[1],hw[2],hw[3]}, l = {lw[0],lw[1],lw[2],lw[3]};
  r.hi = __builtin_bit_cast(bf16x8, h);
  r.lo = __builtin_bit_cast(bf16x8, l);
  return r;
}

#define MFMA(A,B,C) __builtin_amdgcn_mfma_f32_16x16x32_bf16((A),(B),(C),0,0,0)

__global__ __launch_bounds__(512, 4)
void fenc_mfma(const float* __restrict__ x, float* __restrict__ out) {
  __shared__ f32x4 red[kWaves][2][64];      // 16 KB: per-wave S^T partials
  const int lane = (int)(threadIdx.x & 63), wid = (int)(threadIdx.x >> 6);
  const int g = lane >> 4, c = lane & 15;

  // XCD strip + CU-pair swizzle. HW round-robins bid over 8 XCDs; within an
  // XCD the dispatch index j = bid/8 walks CUs. Map j -> (j%32)*2 + j/32 so
  // the two blocks that land on one CU (j and j+32) get ADJACENT tiles.
  const int xcd = (int)(blockIdx.x % kXCD);
  const int j   = (int)(blockIdx.x / kXCD);
  const int vb  = xcd * kCPX + (j % 32) * 2 + (j / 32);
  const int t0g = vb * kTilesT;
  const int b   = t0g / kS, t0 = t0g % kS;
  const float* __restrict__ xb = x + (size_t)b*kS*kH;
  float* __restrict__ ob = out + (size_t)b*kS*kH;
  const int hw0 = kHW * wid;

  // ---- QK^T (swapped: A = K windows, B = Q), k-split over H ----
  const int ra = (t0 + 1 + c  < kS) ? (t0 + 1 + c)  : (kS - 1);
  const int rb = (t0 + 17 + c < kS) ? (t0 + 17 + c) : (kS - 1);
  const float* qp  = xb + (size_t)(t0 + c)*kH + hw0;
  const float* kpa = xb + (size_t)ra*kH + hw0;
  const float* kpb = xb + (size_t)rb*kH + hw0;

  // 6 independent accumulation chains (depth 4 each) -> MFMA pipelines.
  f32x4 aHH = {0.f,0.f,0.f,0.f}, aHL = aHH, aLH = aHH;
  f32x4 bHH = aHH, bHL = aHH, bLH = aHH;
  __builtin_amdgcn_s_setprio(1);
#pragma unroll
  for (int ks = 0; ks < 4; ++ks) {
    const int off = ks*32 + g*8;
    float4 q0 = *(const float4*)(qp  + off), q1 = *(const float4*)(qp  + off + 4);
    float4 a0 = *(const float4*)(kpa + off), a1 = *(const float4*)(kpa + off + 4);
    float4 b0 = *(const float4*)(kpb + off), b1 = *(const float4*)(kpb + off + 4);
    Frag2 fq = split2(q0, q1), fa = split2(a0, a1), fb = split2(b0, b1);
    aHH = MFMA(fa.hi, fq.hi, aHH);
    aHL = MFMA(fa.hi, fq.lo, aHL);
    aLH = MFMA(fa.lo, fq.hi, aLH);
    bHH = MFMA(fb.hi, fq.hi, bHH);
    bHL = MFMA(fb.hi, fq.lo, bHL);
    bLH = MFMA(fb.lo, fq.hi, bLH);
  }
  __builtin_amdgcn_s_setprio(0);
  f32x4 accA = (aHH + aHL) + aLH;
  f32x4 accB = (bHH + bHL) + bLH;

  // ---- V row pointers ----
  const float* vrow[8];
#pragma unroll
  for (int i = 0; i < 8; ++i) {
    const int rv = t0 + 1 + 8*g + i;
    vrow[i] = xb + (size_t)((rv < kS) ? rv : (kS - 1))*kH + hw0 + c;
  }

  // ---- cross-wave reduce of S^T partials (b128, lane-linear) ----
  red[wid][0][lane] = accA;
  red[wid][1][lane] = accB;
  __syncthreads();
#pragma unroll
  for (int w = 0; w < kWaves; ++w) {
    if (w != wid) {
      accA += red[w][0][lane];
      accB += red[w][1][lane];
    }
  }

  // ---- softmax (per lane: all 32 windows of t = t0+c) ----
  float p[2][4];
  float vmax = -1e30f;
#pragma unroll
  for (int T = 0; T < 2; ++T)
#pragma unroll
    for (int r = 0; r < 4; ++r) {
      const int w = 16*T + 4*g + r;
      const bool val = (w >= c) && (w < c + 16) && (t0 + 1 + w < kS);
      const float sv = val ? (T ? accB[r] : accA[r]) : -1e30f;
      p[T][r] = sv;
      vmax = fmaxf(vmax, sv);
    }
  vmax = fmaxf(vmax, __shfl_xor(vmax, 16, 64));
  vmax = fmaxf(vmax, __shfl_xor(vmax, 32, 64));
  float psum = 0.f;
#pragma unroll
  for (int T = 0; T < 2; ++T)
#pragma unroll
    for (int r = 0; r < 4; ++r) {
      const int w = 16*T + 4*g + r;
      const bool val = (w >= c) && (w < c + 16) && (t0 + 1 + w < kS);
      const float e = val ? __expf(p[T][r] - vmax) : 0.f;
      p[T][r] = e;
      psum += e;
    }
  psum += __shfl_xor(psum, 16, 64);
  psum += __shfl_xor(psum, 32, 64);
  const float inv = (psum > 0.f) ? (1.f / psum) : 0.f;
#pragma unroll
  for (int T = 0; T < 2; ++T)
#pragma unroll
    for (int r = 0; r < 4; ++r) p[T][r] *= inv;

  // ---- build P^T A-frag: lane needs P[t=c][w = 8g+i], i=0..7 ----
  const int se = (g & 1)*32 + c, so = se + 16;
  float slot[8];
#pragma unroll
  for (int r = 0; r < 4; ++r) {
    const float e0 = __shfl(p[0][r], se, 64), e1 = __shfl(p[1][r], se, 64);
    const float o0 = __shfl(p[0][r], so, 64), o1 = __shfl(p[1][r], so, 64);
    slot[r]     = (g >> 1) ? e1 : e0;
    slot[4 + r] = (g >> 1) ? o1 : o0;
  }
  u32x4 pw = { pkbf(slot[0],slot[1]), pkbf(slot[2],slot[3]),
               pkbf(slot[4],slot[5]), pkbf(slot[6],slot[7]) };
  const bf16x8 pa = __builtin_bit_cast(bf16x8, pw);

  // ---- PV: O[t][h] = sum_w P[t][w] V[w][h] over this wave's 128 h-cols ----
  f32x4 o[8];
  __builtin_amdgcn_s_setprio(1);
#pragma unroll
  for (int nt = 0; nt < 8; ++nt) {
    float vf[8];
#pragma unroll
    for (int i = 0; i < 8; ++i) vf[i] = vrow[i][16*nt];
    u32x4 vw = { pkbf(vf[0],vf[1]), pkbf(vf[2],vf[3]),
                 pkbf(vf[4],vf[5]), pkbf(vf[6],vf[7]) };
    const bf16x8 vfrag = __builtin_bit_cast(bf16x8, vw);
    f32x4 z = {0.f,0.f,0.f,0.f};
    o[nt] = MFMA(pa, vfrag, z);
  }
  __builtin_amdgcn_s_setprio(0);

  // ---- store (NON-TEMPORAL: keep output out of the per-XCD L2) ----
  float* orow[4];
#pragma unroll
  for (int r = 0; r < 4; ++r)
    orow[r] = ob + (size_t)(t0 + 4*g + r)*kH + hw0 + c;
#pragma unroll
  for (int nt = 0; nt < 8; ++nt)
#pragma unroll
    for (int r = 0; r < 4; ++r)
      __builtin_nontemporal_store(o[nt][r], &orow[r][16*nt]);
}

extern "C" void kernel_launch(void* const* d_in, const int* in_sizes, int n_in,
                              void* d_out, int out_size, void* d_ws, size_t ws_size,
                              hipStream_t stream) {
  const float* x = (const float*)d_in[0];
  float* out = (float*)d_out;
  hipLaunchKernelGGL(fenc_mfma, dim3(kBlocks), dim3(512), 0, stream, x, out);
}

// Round 19
// 24.298 us; speedup vs baseline: 2.9091x; 1.0512x over previous
//
#include <hip/hip_runtime.h>

// FutureEncoder as banded flash-attention on MFMA (bf16 split-precision).
// out[b,t,:] = softmax_j(x[t]·x[t+1+j]) · x[t+1+j], j in [0,16), fp32 I/O.
//
// Round 19 = R13 + "V from LDS restage": the V-gather (16KB/wave, 40% of all
// L2/L3 reads) re-fetched exactly the K rows/cols this wave already loaded
// for QK^T. Now each wave packs its K floats to bf16 during QK and writes
// them to a private 8KB LDS slice (b128, XOR-swizzled); PV reads V-frags as
// ds_read_u16 from its OWN slice (same-wave visibility -> no new barrier).
// Cache-path reads drop ~164 -> ~98 MB/pass; 64 VMEM ops/wave removed.
// Swizzle: byte col ^= ((w&7)<<4) ^ ((w>>3)<<5); reads land 32 distinct
// banks (conflict-free), writes at the b128 floor.

typedef float f32x4 __attribute__((ext_vector_type(4)));
typedef unsigned int u32;
typedef u32 u32x4 __attribute__((ext_vector_type(4)));
typedef short bf16x8 __attribute__((ext_vector_type(8)));

namespace {
constexpr int kB = 2, kS = 4096, kH = 1024;
constexpr int kWaves = 8;                    // 512 threads
constexpr int kTilesT = 16;                  // t's per block
constexpr int kBlocks = kB * kS / kTilesT;   // 512 -> 2 blocks/CU
constexpr int kXCD = 8;
constexpr int kHW = kH / kWaves;             // 128 h-cols per wave
}

__device__ __forceinline__ u32 f32u(float x){ return __builtin_bit_cast(u32, x); }
__device__ __forceinline__ float uf32(u32 x){ return __builtin_bit_cast(float, x); }
__device__ __forceinline__ u32 pkbf(float a, float b){ return (f32u(b)&0xFFFF0000u)|(f32u(a)>>16); }

struct Frag2 { bf16x8 hi, lo; };
__device__ __forceinline__ Frag2 split2(float4 u, float4 v) {
  float fu[8] = {u.x,u.y,u.z,u.w,v.x,v.y,v.z,v.w};
  u32 hw[4], lw[4];
#pragma unroll
  for (int i = 0; i < 4; ++i) {
    float a = fu[2*i], b = fu[2*i+1];
    u32 ua = f32u(a), ub = f32u(b);
    hw[i] = (ub & 0xFFFF0000u) | (ua >> 16);
    float la = a - uf32(ua & 0xFFFF0000u);
    float lb = b - uf32(ub & 0xFFFF0000u);
    lw[i] = (f32u(lb) & 0xFFFF0000u) | (f32u(la) >> 16);
  }
  Frag2 r;
  u32x4 h = {hw[0],hw[1],hw[2],hw[3]}, l = {lw[0],lw[1],lw[2],lw[3]};
  r.hi = __builtin_bit_cast(bf16x8, h);
  r.lo = __builtin_bit_cast(bf16x8, l);
  return r;
}

#define MFMA(A,B,C) __builtin_amdgcn_mfma_f32_16x16x32_bf16((A),(B),(C),0,0,0)

__global__ __launch_bounds__(512, 4)
void fenc_mfma(const float* __restrict__ x, float* __restrict__ out) {
  __shared__ f32x4 red[kWaves][2][64];           // 16 KB: S^T partials
  __shared__ __align__(16) unsigned short kst[kWaves][32 * 128];  // 64 KB: bf16 K-stage
  const int lane = (int)(threadIdx.x & 63), wid = (int)(threadIdx.x >> 6);
  const int g = lane >> 4, c = lane & 15;

  // XCD strip swizzle (512 % 8 == 0 -> bijective)
  const int vb  = (int)(blockIdx.x % kXCD)*(kBlocks/kXCD) + (int)(blockIdx.x / kXCD);
  const int t0g = vb * kTilesT;
  const int b   = t0g / kS, t0 = t0g % kS;
  const float* __restrict__ xb = x + (size_t)b*kS*kH;
  float* __restrict__ ob = out + (size_t)b*kS*kH;
  const int hw0 = kHW * wid;

  // ---- QK^T (swapped: A = K windows, B = Q) + K->LDS bf16 stage ----
  const int ra = (t0 + 1 + c  < kS) ? (t0 + 1 + c)  : (kS - 1);
  const int rb = (t0 + 17 + c < kS) ? (t0 + 17 + c) : (kS - 1);
  const float* qp  = xb + (size_t)(t0 + c)*kH + hw0;
  const float* kpa = xb + (size_t)ra*kH + hw0;
  const float* kpb = xb + (size_t)rb*kH + hw0;
  unsigned short* ks_base = &kst[wid][0];

  // row w (0..31) of the stage holds x[t0+1+w][hw0..hw0+128) as bf16.
  // element index = w*128 + (m ^ xw16), xw16 = ((w&7)<<3) ^ ((w>>3)<<4).
  const int wA = c,      xA = ((wA & 7) << 3) ^ ((wA >> 3) << 4);
  const int wB = 16 + c, xB = ((wB & 7) << 3) ^ ((wB >> 3) << 4);

  f32x4 aHH = {0.f,0.f,0.f,0.f}, aHL = aHH, aLH = aHH;
  f32x4 bHH = aHH, bHL = aHH, bLH = aHH;
  __builtin_amdgcn_s_setprio(1);
#pragma unroll
  for (int ks = 0; ks < 4; ++ks) {
    const int off = ks*32 + g*8;
    float4 q0 = *(const float4*)(qp  + off), q1 = *(const float4*)(qp  + off + 4);
    float4 a0 = *(const float4*)(kpa + off), a1 = *(const float4*)(kpa + off + 4);
    float4 b0 = *(const float4*)(kpb + off), b1 = *(const float4*)(kpb + off + 4);

    // Stage K rows to LDS (bf16 truncation == the old V packing)
    u32x4 pkA = { pkbf(a0.x,a0.y), pkbf(a0.z,a0.w), pkbf(a1.x,a1.y), pkbf(a1.z,a1.w) };
    u32x4 pkB = { pkbf(b0.x,b0.y), pkbf(b0.z,b0.w), pkbf(b1.x,b1.y), pkbf(b1.z,b1.w) };
    *(u32x4*)(ks_base + wA*128 + (off ^ xA)) = pkA;
    *(u32x4*)(ks_base + wB*128 + (off ^ xB)) = pkB;

    Frag2 fq = split2(q0, q1), fa = split2(a0, a1), fb = split2(b0, b1);
    aHH = MFMA(fa.hi, fq.hi, aHH);
    aHL = MFMA(fa.hi, fq.lo, aHL);
    aLH = MFMA(fa.lo, fq.hi, aLH);
    bHH = MFMA(fb.hi, fq.hi, bHH);
    bHL = MFMA(fb.hi, fq.lo, bHL);
    bLH = MFMA(fb.lo, fq.hi, bLH);
  }
  __builtin_amdgcn_s_setprio(0);
  f32x4 accA = (aHH + aHL) + aLH;
  f32x4 accB = (bHH + bHL) + bLH;

  // ---- cross-wave reduce of S^T partials ----
  red[wid][0][lane] = accA;
  red[wid][1][lane] = accB;
  __syncthreads();
#pragma unroll
  for (int w = 0; w < kWaves; ++w) {
    if (w != wid) {
      accA += red[w][0][lane];
      accB += red[w][1][lane];
    }
  }

  // ---- softmax (per lane: all 32 windows of t = t0+c) ----
  float p[2][4];
  float vmax = -1e30f;
#pragma unroll
  for (int T = 0; T < 2; ++T)
#pragma unroll
    for (int r = 0; r < 4; ++r) {
      const int w = 16*T + 4*g + r;
      const bool val = (w >= c) && (w < c + 16) && (t0 + 1 + w < kS);
      const float sv = val ? (T ? accB[r] : accA[r]) : -1e30f;
      p[T][r] = sv;
      vmax = fmaxf(vmax, sv);
    }
  vmax = fmaxf(vmax, __shfl_xor(vmax, 16, 64));
  vmax = fmaxf(vmax, __shfl_xor(vmax, 32, 64));
  float psum = 0.f;
#pragma unroll
  for (int T = 0; T < 2; ++T)
#pragma unroll
    for (int r = 0; r < 4; ++r) {
      const int w = 16*T + 4*g + r;
      const bool val = (w >= c) && (w < c + 16) && (t0 + 1 + w < kS);
      const float e = val ? __expf(p[T][r] - vmax) : 0.f;
      p[T][r] = e;
      psum += e;
    }
  psum += __shfl_xor(psum, 16, 64);
  psum += __shfl_xor(psum, 32, 64);
  const float inv = (psum > 0.f) ? (1.f / psum) : 0.f;
#pragma unroll
  for (int T = 0; T < 2; ++T)
#pragma unroll
    for (int r = 0; r < 4; ++r) p[T][r] *= inv;

  // ---- build P^T A-frag: lane needs P[t=c][w = 8g+i], i=0..7 ----
  const int se = (g & 1)*32 + c, so = se + 16;
  float slot[8];
#pragma unroll
  for (int r = 0; r < 4; ++r) {
    const float e0 = __shfl(p[0][r], se, 64), e1 = __shfl(p[1][r], se, 64);
    const float o0 = __shfl(p[0][r], so, 64), o1 = __shfl(p[1][r], so, 64);
    slot[r]     = (g >> 1) ? e1 : e0;
    slot[4 + r] = (g >> 1) ? o1 : o0;
  }
  u32x4 pw = { pkbf(slot[0],slot[1]), pkbf(slot[2],slot[3]),
               pkbf(slot[4],slot[5]), pkbf(slot[6],slot[7]) };
  const bf16x8 pa = __builtin_bit_cast(bf16x8, pw);

  // ---- PV: V-frags from this wave's OWN LDS stage (no global reads) ----
  // lane (g,c), tile nt: needs V[w = 8g+i][m = 16nt+c], i = 0..7.
  f32x4 o[8];
  __builtin_amdgcn_s_setprio(1);
#pragma unroll
  for (int nt = 0; nt < 8; ++nt) {
    const int m = 16*nt + c;
    u32 vwj[4];
#pragma unroll
    for (int jj = 0; jj < 4; ++jj) {
      const int w0 = 8*g + 2*jj, w1 = w0 + 1;
      const int x0 = (((w0 & 7) << 3) ^ (g << 4));
      const int x1 = (((w1 & 7) << 3) ^ (g << 4));
      const u32 lo = ks_base[w0*128 + (m ^ x0)];
      const u32 hi = ks_base[w1*128 + (m ^ x1)];
      vwj[jj] = lo | (hi << 16);
    }
    u32x4 vw = { vwj[0], vwj[1], vwj[2], vwj[3] };
    const bf16x8 vfrag = __builtin_bit_cast(bf16x8, vw);
    f32x4 z = {0.f,0.f,0.f,0.f};
    o[nt] = MFMA(pa, vfrag, z);
  }
  __builtin_amdgcn_s_setprio(0);

  // ---- store (non-temporal: output is never re-read) ----
  float* orow[4];
#pragma unroll
  for (int r = 0; r < 4; ++r)
    orow[r] = ob + (size_t)(t0 + 4*g + r)*kH + hw0 + c;
#pragma unroll
  for (int nt = 0; nt < 8; ++nt)
#pragma unroll
    for (int r = 0; r < 4; ++r)
      __builtin_nontemporal_store(o[nt][r], &orow[r][16*nt]);
}

extern "C" void kernel_launch(void* const* d_in, const int* in_sizes, int n_in,
                              void* d_out, int out_size, void* d_ws, size_t ws_size,
                              hipStream_t stream) {
  const float* x = (const float*)d_in[0];
  float* out = (float*)d_out;
  hipLaunchKernelGGL(fenc_mfma, dim3(kBlocks), dim3(512), 0, stream, x, out);
}